// Round 2
// baseline (203.213 us; speedup 1.0000x reference)
//
#include <hip/hip_runtime.h>

typedef _Float16 half_t;
typedef _Float16 hx8 __attribute__((ext_vector_type(8)));
typedef _Float16 hx4 __attribute__((ext_vector_type(4)));
typedef float fx4 __attribute__((ext_vector_type(4)));

#define LOG2E 1.44269504088896f
#define TAU 0.1f

// ---------------- Kernel 1: T = relu(Z@W1+b1)@W2+b2  -> fp16 ----------------
// 512 blocks x 16 rows, 256 threads (2 blocks/CU, 2 waves/SIMD for latency hiding).
__global__ __launch_bounds__(256) void mlp_kernel(
    const float* __restrict__ Z, const float* __restrict__ W1,
    const float* __restrict__ b1, const float* __restrict__ W2,
    const float* __restrict__ b2, half_t* __restrict__ T)
{
  __shared__ float Hs[16*132];
  const int tid = threadIdx.x;
  const int row = tid & 15;             // local row
  const int cg  = tid >> 4;             // col group: cols cg*8 .. cg*8+7
  const int rb  = blockIdx.x * 16;

  float acc[8];
#pragma unroll
  for (int cc=0;cc<8;++cc) acc[cc] = b1[cg*8+cc];

  for (int k=0;k<128;k+=4) {
    fx4 z = *(const fx4*)(Z + (size_t)(rb + row)*128 + k);
#pragma unroll
    for (int kk=0;kk<4;++kk) {
      fx4 wA = *(const fx4*)(W1 + (k+kk)*128 + cg*8);
      fx4 wB = *(const fx4*)(W1 + (k+kk)*128 + cg*8 + 4);
      float zz = z[kk];
#pragma unroll
      for (int cc=0;cc<4;++cc) { acc[cc] += zz*wA[cc]; acc[4+cc] += zz*wB[cc]; }
    }
  }
#pragma unroll
  for (int cc=0;cc<8;++cc) {
    float h = acc[cc];
    Hs[row*132 + cg*8 + cc] = h > 0.f ? h : 0.f;
  }
  __syncthreads();

#pragma unroll
  for (int cc=0;cc<8;++cc) acc[cc] = b2[cg*8+cc];

  for (int k=0;k<128;k+=4) {
    fx4 z = *(const fx4*)(&Hs[row*132 + k]);
#pragma unroll
    for (int kk=0;kk<4;++kk) {
      fx4 wA = *(const fx4*)(W2 + (k+kk)*128 + cg*8);
      fx4 wB = *(const fx4*)(W2 + (k+kk)*128 + cg*8 + 4);
      float zz = z[kk];
#pragma unroll
      for (int cc=0;cc<4;++cc) { acc[cc] += zz*wA[cc]; acc[4+cc] += zz*wB[cc]; }
    }
  }
  hx8 hv;
#pragma unroll
  for (int cc=0;cc<8;++cc) hv[cc] = (half_t)acc[cc];
  *(hx8*)(T + (size_t)(rb + row)*128 + cg*8) = hv;
}

// ---------------- Kernel 2: Zt[d][n] = (fp16) Z[n][d] ----------------
__global__ __launch_bounds__(256) void ztrans_kernel(
    const float* __restrict__ Z, half_t* __restrict__ Zth)
{
  __shared__ float tile[64*36];
  const int tid = threadIdx.x;
  const int nb = blockIdx.x >> 2;
  const int db = blockIdx.x & 3;
#pragma unroll
  for (int i=0;i<2;++i) {
    int fid = i*256 + tid;
    int r = fid >> 3, c4 = (fid & 7) * 4;
    *(fx4*)(&tile[r*36 + c4]) = *(const fx4*)(Z + (size_t)(nb*64 + r)*128 + db*32 + c4);
  }
  __syncthreads();
  const int cr = tid >> 3, j = tid & 7, n0 = j*8;
  hx8 hv;
#pragma unroll
  for (int idx=0;idx<8;++idx) hv[idx] = (half_t)tile[(n0+idx)*36 + cr];
  *(hx8*)(Zth + (size_t)(db*32 + cr)*8192 + nb*64 + n0) = hv;
}

// ---------------- Kernel 3: flash attention partials (transposed scores) ----
// grid 512 = 64 query-blocks(128 rows) x 8 key-splits(1024 keys = 16 tiles of 64)
// 4 waves x 32 queries/wave. Scores computed TRANSPOSED: St[key][query]
// (A = key rows from LDS, B = query rows pinned in regs). Softmax key-reduction
// is 16 in-lane values + 2 cross-lane hops (xor16/xor32). PV: O^T = Zt_tile @ P^T.
__global__ __launch_bounds__(256,3) void flash_kernel(
    const half_t* __restrict__ T, const half_t* __restrict__ Zt,
    half_t* __restrict__ Pacc, float* __restrict__ Pm, float* __restrict__ Pl)
{
  __shared__ half_t Tks[16*512];        // frags (mt,ks): key-tile rows, A for scores
  __shared__ half_t Zts[16*512];        // frags (mtd,ks2): Zt rows, A for PV
  __shared__ half_t Ps[4][32*72];       // per-wave P^T roundtrip: [query][key], stride 72
  const int tid = threadIdx.x;
  const int w = tid >> 6, lane = tid & 63;
  const int q = lane >> 4, c = lane & 15;
  const int bx = blockIdx.x;
  const int qb = bx >> 3, kh = bx & 7;
  const int wrow = qb*128 + w*32;

  // B-frags (query rows) pinned: B[n=c][k=q*8+j] = T[wrow+16nt+c][32ks+8q+j]
  hx8 bq[2][4];
#pragma unroll
  for (int nt=0;nt<2;++nt)
#pragma unroll
    for (int ks=0;ks<4;++ks)
      bq[nt][ks] = *(const hx8*)(T + (size_t)(wrow + nt*16 + c)*128 + ks*32 + q*8);

  fx4 oacc[8][2];                       // O^T[d=16mtd+4q+i][query=16nt+c]
#pragma unroll
  for (int mtd=0;mtd<8;++mtd)
#pragma unroll
    for (int nt=0;nt<2;++nt) oacc[mtd][nt] = (fx4){0.f,0.f,0.f,0.f};
  float m_run[2] = {-1e30f,-1e30f};
  float l_run[2] = {0.f,0.f};

  for (int t=0;t<16;++t) {
    const int kt0 = kh*1024 + t*64;
    __syncthreads();
#pragma unroll
    for (int i=0;i<8;++i) {
      int f = w*8 + i;
      if (f < 16) {
        int mt = f >> 2, ks = f & 3;    // A[m=key c][k=dim]
        hx8 v = *(const hx8*)(T + (size_t)(kt0 + mt*16 + c)*128 + ks*32 + q*8);
        *(hx8*)(&Tks[f*512 + lane*8]) = v;
      } else {
        int f2 = f - 16, mtd = f2 >> 1, ks2 = f2 & 1;  // A[m=d c][k=key]
        hx8 v = *(const hx8*)(Zt + (size_t)(mtd*16 + c)*8192 + kt0 + ks2*32 + q*8);
        *(hx8*)(&Zts[f2*512 + lane*8]) = v;
      }
    }
    __syncthreads();

    // ---- scores: St[64 keys x 32 queries], C: row=key=4q+i(+16mt), col=query=c ----
    fx4 sacc[4][2];
#pragma unroll
    for (int mt=0;mt<4;++mt)
#pragma unroll
      for (int nt=0;nt<2;++nt) sacc[mt][nt] = (fx4){0.f,0.f,0.f,0.f};
#pragma unroll
    for (int ks=0;ks<4;++ks)
#pragma unroll
      for (int mt=0;mt<4;++mt) {
        hx8 ak = *(const hx8*)(&Tks[(mt*4+ks)*512 + lane*8]);
        sacc[mt][0] = __builtin_amdgcn_mfma_f32_16x16x32_f16(ak, bq[0][ks], sacc[mt][0], 0,0,0);
        sacc[mt][1] = __builtin_amdgcn_mfma_f32_16x16x32_f16(ak, bq[1][ks], sacc[mt][1], 0,0,0);
      }

    // ---- online softmax per query (=per lane column, per nt) ----
#pragma unroll
    for (int nt=0;nt<2;++nt) {
      float mx = -1e30f;
#pragma unroll
      for (int mt=0;mt<4;++mt)
#pragma unroll
        for (int i=0;i<4;++i) mx = fmaxf(mx, sacc[mt][nt][i]);
      mx = fmaxf(mx, __shfl_xor(mx, 16, 64));
      mx = fmaxf(mx, __shfl_xor(mx, 32, 64));
      float mnew = fmaxf(m_run[nt], mx);
      float alpha = __builtin_amdgcn_exp2f((m_run[nt]-mnew)*LOG2E);
      m_run[nt] = mnew;
      float nb = mnew*LOG2E;
      float rs = 0.f;
#pragma unroll
      for (int mt=0;mt<4;++mt) {
        hx4 pk;
#pragma unroll
        for (int i=0;i<4;++i) {
          float p = __builtin_amdgcn_exp2f(sacc[mt][nt][i]*LOG2E - nb);
          rs += p;
          pk[i] = (half_t)p;
        }
        *(hx4*)(&Ps[w][(nt*16 + c)*72 + mt*16 + 4*q]) = pk;   // 8B store, keys 4q..4q+3
      }
      rs += __shfl_xor(rs, 16, 64);
      rs += __shfl_xor(rs, 32, 64);
      l_run[nt] = l_run[nt]*alpha + rs;
#pragma unroll
      for (int mtd=0;mtd<8;++mtd)
#pragma unroll
        for (int i=0;i<4;++i) oacc[mtd][nt][i] *= alpha;
    }

    // ---- PV: O^T += Zt_tile @ P^T (Ps same-wave; compiler orders via lgkmcnt) ----
#pragma unroll
    for (int ks2=0;ks2<2;++ks2) {
      hx8 bp0 = *(const hx8*)(&Ps[w][(c     )*72 + ks2*32 + q*8]);
      hx8 bp1 = *(const hx8*)(&Ps[w][(16 + c)*72 + ks2*32 + q*8]);
#pragma unroll
      for (int mtd=0;mtd<8;++mtd) {
        hx8 az = *(const hx8*)(&Zts[(mtd*2+ks2)*512 + lane*8]);
        oacc[mtd][0] = __builtin_amdgcn_mfma_f32_16x16x32_f16(az, bp0, oacc[mtd][0], 0,0,0);
        oacc[mtd][1] = __builtin_amdgcn_mfma_f32_16x16x32_f16(az, bp1, oacc[mtd][1], 0,0,0);
      }
    }
  }

  // epilogue: normalized fp16 partials (row-major [query][d]) + (m,l)
#pragma unroll
  for (int nt=0;nt<2;++nt) {
    float inv = 1.0f / l_run[nt];
    const size_t rowg = (size_t)(bx*128 + w*32 + nt*16 + c);
#pragma unroll
    for (int mtd=0;mtd<8;++mtd) {
      hx4 ov;
#pragma unroll
      for (int i=0;i<4;++i) ov[i] = (half_t)(oacc[mtd][nt][i]*inv);
      *(hx4*)(Pacc + rowg*128 + mtd*16 + 4*q) = ov;
    }
    if (q == 0) {
      Pm[rowg] = m_run[nt];
      Pl[rowg] = l_run[nt];
    }
  }
}

// ---------------- Kernel 4: merge 8 key-split partials ----------------
__global__ __launch_bounds__(256) void merge_kernel(
    const float* __restrict__ Z, const half_t* __restrict__ Pacc,
    const float* __restrict__ Pm, const float* __restrict__ Pl,
    float* __restrict__ out)
{
  const int th = blockIdx.x*256 + threadIdx.x;
  const int r = th >> 5, cg = th & 31;
  const int qb = r >> 7, rr = r & 127;
  float mk[8], lk[8];
  float M = -1e30f;
#pragma unroll
  for (int k=0;k<8;++k) {
    int p = qb*8 + k;
    mk[k] = Pm[p*128 + rr];
    lk[k] = Pl[p*128 + rr];
    M = fmaxf(M, mk[k]);
  }
  float L = 0.f, wk[8];
#pragma unroll
  for (int k=0;k<8;++k) { wk[k] = lk[k]*__builtin_amdgcn_exp2f((mk[k]-M)*LOG2E); L += wk[k]; }
  float o0=0.f,o1=0.f,o2=0.f,o3=0.f;
#pragma unroll
  for (int k=0;k<8;++k) {
    int p = qb*8 + k;
    hx4 v = *(const hx4*)(Pacc + ((size_t)p*128 + rr)*128 + cg*4);
    o0 += wk[k]*(float)v[0]; o1 += wk[k]*(float)v[1];
    o2 += wk[k]*(float)v[2]; o3 += wk[k]*(float)v[3];
  }
  float invL = 1.0f / L;
  fx4 zv = *(const fx4*)(Z + (size_t)r*128 + cg*4);
  fx4 res;
  res[0] = (1.f-TAU)*zv[0] + TAU*o0*invL;
  res[1] = (1.f-TAU)*zv[1] + TAU*o1*invL;
  res[2] = (1.f-TAU)*zv[2] + TAU*o2*invL;
  res[3] = (1.f-TAU)*zv[3] + TAU*o3*invL;
  *(fx4*)(out + (size_t)r*128 + cg*4) = res;
}

extern "C" void kernel_launch(void* const* d_in, const int* in_sizes, int n_in,
                              void* d_out, int out_size, void* d_ws, size_t ws_size,
                              hipStream_t stream) {
  const float* Z  = (const float*)d_in[0];
  const float* W1 = (const float*)d_in[1];
  const float* b1 = (const float*)d_in[2];
  const float* W2 = (const float*)d_in[3];
  const float* b2 = (const float*)d_in[4];
  float* out = (float*)d_out;

  char* ws = (char*)d_ws;
  half_t* Thi  = (half_t*)(ws);                                   // 2 MB
  half_t* Zth  = (half_t*)(ws + (size_t)2*1024*1024);             // 2 MB
  half_t* Pacc = (half_t*)(ws + (size_t)4*1024*1024);             // 16 MB
  float*  Pm   = (float*)(ws + (size_t)4*1024*1024 + (size_t)512*128*128*2);
  float*  Pl   = Pm + 512*128;

  hipLaunchKernelGGL(mlp_kernel,   dim3(512),  dim3(256), 0, stream, Z, W1, b1, W2, b2, Thi);
  hipLaunchKernelGGL(ztrans_kernel,dim3(512),  dim3(256), 0, stream, Z, Zth);
  hipLaunchKernelGGL(flash_kernel, dim3(512),  dim3(256), 0, stream, Thi, Zth, Pacc, Pm, Pl);
  hipLaunchKernelGGL(merge_kernel, dim3(1024), dim3(256), 0, stream, Z, Pacc, Pm, Pl, out);
}

// Round 3
// 180.106 us; speedup vs baseline: 1.1283x; 1.1283x over previous
//
#include <hip/hip_runtime.h>

typedef _Float16 half_t;
typedef _Float16 hx8 __attribute__((ext_vector_type(8)));
typedef _Float16 hx4 __attribute__((ext_vector_type(4)));
typedef float fx4 __attribute__((ext_vector_type(4)));

#define LOG2E 1.44269504088896f
#define TAU 0.1f

// ---------------- Kernel 1: T = relu(Z@W1+b1)@W2+b2  -> fp16 ----------------
__global__ __launch_bounds__(256) void mlp_kernel(
    const float* __restrict__ Z, const float* __restrict__ W1,
    const float* __restrict__ b1, const float* __restrict__ W2,
    const float* __restrict__ b2, half_t* __restrict__ T)
{
  __shared__ float Hs[16*132];
  const int tid = threadIdx.x;
  const int row = tid & 15;
  const int cg  = tid >> 4;
  const int rb  = blockIdx.x * 16;

  float acc[8];
#pragma unroll
  for (int cc=0;cc<8;++cc) acc[cc] = b1[cg*8+cc];

  for (int k=0;k<128;k+=4) {
    fx4 z = *(const fx4*)(Z + (size_t)(rb + row)*128 + k);
#pragma unroll
    for (int kk=0;kk<4;++kk) {
      fx4 wA = *(const fx4*)(W1 + (k+kk)*128 + cg*8);
      fx4 wB = *(const fx4*)(W1 + (k+kk)*128 + cg*8 + 4);
      float zz = z[kk];
#pragma unroll
      for (int cc=0;cc<4;++cc) { acc[cc] += zz*wA[cc]; acc[4+cc] += zz*wB[cc]; }
    }
  }
#pragma unroll
  for (int cc=0;cc<8;++cc) {
    float h = acc[cc];
    Hs[row*132 + cg*8 + cc] = h > 0.f ? h : 0.f;
  }
  __syncthreads();

#pragma unroll
  for (int cc=0;cc<8;++cc) acc[cc] = b2[cg*8+cc];

  for (int k=0;k<128;k+=4) {
    fx4 z = *(const fx4*)(&Hs[row*132 + k]);
#pragma unroll
    for (int kk=0;kk<4;++kk) {
      fx4 wA = *(const fx4*)(W2 + (k+kk)*128 + cg*8);
      fx4 wB = *(const fx4*)(W2 + (k+kk)*128 + cg*8 + 4);
      float zz = z[kk];
#pragma unroll
      for (int cc=0;cc<4;++cc) { acc[cc] += zz*wA[cc]; acc[4+cc] += zz*wB[cc]; }
    }
  }
  hx8 hv;
#pragma unroll
  for (int cc=0;cc<8;++cc) hv[cc] = (half_t)acc[cc];
  *(hx8*)(T + (size_t)(rb + row)*128 + cg*8) = hv;
}

// ---------------- Kernel 2: Zt[d][n] = (fp16) Z[n][d] ----------------
__global__ __launch_bounds__(256) void ztrans_kernel(
    const float* __restrict__ Z, half_t* __restrict__ Zth)
{
  __shared__ float tile[64*36];
  const int tid = threadIdx.x;
  const int nb = blockIdx.x >> 2;
  const int db = blockIdx.x & 3;
#pragma unroll
  for (int i=0;i<2;++i) {
    int fid = i*256 + tid;
    int r = fid >> 3, c4 = (fid & 7) * 4;
    *(fx4*)(&tile[r*36 + c4]) = *(const fx4*)(Z + (size_t)(nb*64 + r)*128 + db*32 + c4);
  }
  __syncthreads();
  const int cr = tid >> 3, j = tid & 7, n0 = j*8;
  hx8 hv;
#pragma unroll
  for (int idx=0;idx<8;++idx) hv[idx] = (half_t)tile[(n0+idx)*36 + cr];
  *(hx8*)(Zth + (size_t)(db*32 + cr)*8192 + nb*64 + n0) = hv;
}

// ---------------- Kernel 3: flash attention partials (reg-prefetch) ---------
// grid 512 = 64 query-blocks(128 rows) x 8 key-splits. 4 waves x 32 queries.
// Tile t+1's fragments are prefetched into VGPRs during tile t's compute so the
// barrier window contains only ds_writes (vmcnt satisfied by then).
__global__ __launch_bounds__(256,2) void flash_kernel(
    const half_t* __restrict__ T, const half_t* __restrict__ Zt,
    half_t* __restrict__ Pacc, float* __restrict__ Pm, float* __restrict__ Pl)
{
  __shared__ half_t Tks[16*512];        // frags (mt,ks): key rows, A for scores
  __shared__ half_t Zts[16*512];        // frags (mtd,ks2): Zt rows, A for PV
  __shared__ half_t Ps[4][32*72];       // per-wave P^T roundtrip
  const int tid = threadIdx.x;
  const int w = tid >> 6, lane = tid & 63;
  const int q = lane >> 4, c = lane & 15;
  const int bx = blockIdx.x;
  const int qb = bx >> 3, kh = bx & 7;
  const int wrow = qb*128 + w*32;

  // B-frags (query rows) pinned: B[n=c][k=q*8+j]
  hx8 bq[2][4];
#pragma unroll
  for (int nt=0;nt<2;++nt)
#pragma unroll
    for (int ks=0;ks<4;++ks)
      bq[nt][ks] = *(const hx8*)(T + (size_t)(wrow + nt*16 + c)*128 + ks*32 + q*8);

  fx4 oacc[8][2];
#pragma unroll
  for (int mtd=0;mtd<8;++mtd)
#pragma unroll
    for (int nt=0;nt<2;++nt) oacc[mtd][nt] = (fx4){0.f,0.f,0.f,0.f};
  float m_run[2] = {-1e30f,-1e30f};
  float l_run[2] = {0.f,0.f};

  hx8 pre[8];                           // prefetch registers (wave-uniform role)
  const int kbase = kh*1024;

  // wave-uniform staging: waves 0,1 own Tks frags 0..15; waves 2,3 own Zts 0..15
  auto load_tile = [&](int kt0) {
    if (w < 2) {
#pragma unroll
      for (int i=0;i<8;++i) {
        int f = w*8 + i, mt = f >> 2, ks = f & 3;
        pre[i] = *(const hx8*)(T + (size_t)(kt0 + mt*16 + c)*128 + ks*32 + q*8);
      }
    } else {
#pragma unroll
      for (int i=0;i<8;++i) {
        int f2 = (w-2)*8 + i, mtd = f2 >> 1, ks2 = f2 & 1;
        pre[i] = *(const hx8*)(Zt + (size_t)(mtd*16 + c)*8192 + kt0 + ks2*32 + q*8);
      }
    }
  };
  auto store_tile = [&]() {
    if (w < 2) {
#pragma unroll
      for (int i=0;i<8;++i) { int f = w*8 + i; *(hx8*)(&Tks[f*512 + lane*8]) = pre[i]; }
    } else {
#pragma unroll
      for (int i=0;i<8;++i) { int f2 = (w-2)*8 + i; *(hx8*)(&Zts[f2*512 + lane*8]) = pre[i]; }
    }
  };

  load_tile(kbase);
  for (int t=0;t<16;++t) {
    __syncthreads();                    // prior tile's LDS reads complete
    store_tile();                       // vmcnt drained long ago (overlapped)
    __syncthreads();                    // tile t ready
    if (t < 15) load_tile(kbase + (t+1)*64);   // async into regs, used next iter

    // ---- scores: St[64 keys x 32 queries] ----
    fx4 sacc[4][2];
#pragma unroll
    for (int mt=0;mt<4;++mt)
#pragma unroll
      for (int nt=0;nt<2;++nt) sacc[mt][nt] = (fx4){0.f,0.f,0.f,0.f};
#pragma unroll
    for (int ks=0;ks<4;++ks)
#pragma unroll
      for (int mt=0;mt<4;++mt) {
        hx8 ak = *(const hx8*)(&Tks[(mt*4+ks)*512 + lane*8]);
        sacc[mt][0] = __builtin_amdgcn_mfma_f32_16x16x32_f16(ak, bq[0][ks], sacc[mt][0], 0,0,0);
        sacc[mt][1] = __builtin_amdgcn_mfma_f32_16x16x32_f16(ak, bq[1][ks], sacc[mt][1], 0,0,0);
      }

    // ---- online softmax per query column ----
#pragma unroll
    for (int nt=0;nt<2;++nt) {
      float mx = -1e30f;
#pragma unroll
      for (int mt=0;mt<4;++mt)
#pragma unroll
        for (int i=0;i<4;++i) mx = fmaxf(mx, sacc[mt][nt][i]);
      mx = fmaxf(mx, __shfl_xor(mx, 16, 64));
      mx = fmaxf(mx, __shfl_xor(mx, 32, 64));
      float mnew = fmaxf(m_run[nt], mx);
      float alpha = __builtin_amdgcn_exp2f((m_run[nt]-mnew)*LOG2E);
      m_run[nt] = mnew;
      float nb = mnew*LOG2E;
      float rs = 0.f;
#pragma unroll
      for (int mt=0;mt<4;++mt) {
        hx4 pk;
#pragma unroll
        for (int i=0;i<4;++i) {
          float p = __builtin_amdgcn_exp2f(sacc[mt][nt][i]*LOG2E - nb);
          rs += p;
          pk[i] = (half_t)p;
        }
        *(hx4*)(&Ps[w][(nt*16 + c)*72 + mt*16 + 4*q]) = pk;
      }
      rs += __shfl_xor(rs, 16, 64);
      rs += __shfl_xor(rs, 32, 64);
      l_run[nt] = l_run[nt]*alpha + rs;
#pragma unroll
      for (int mtd=0;mtd<8;++mtd)
#pragma unroll
        for (int i=0;i<4;++i) oacc[mtd][nt][i] *= alpha;
    }

    // ---- PV: O^T += Zt_tile @ P^T ----
#pragma unroll
    for (int ks2=0;ks2<2;++ks2) {
      hx8 bp0 = *(const hx8*)(&Ps[w][(c     )*72 + ks2*32 + q*8]);
      hx8 bp1 = *(const hx8*)(&Ps[w][(16 + c)*72 + ks2*32 + q*8]);
#pragma unroll
      for (int mtd=0;mtd<8;++mtd) {
        hx8 az = *(const hx8*)(&Zts[(mtd*2+ks2)*512 + lane*8]);
        oacc[mtd][0] = __builtin_amdgcn_mfma_f32_16x16x32_f16(az, bp0, oacc[mtd][0], 0,0,0);
        oacc[mtd][1] = __builtin_amdgcn_mfma_f32_16x16x32_f16(az, bp1, oacc[mtd][1], 0,0,0);
      }
    }
  }

  // epilogue: normalized fp16 partials + (m,l)
#pragma unroll
  for (int nt=0;nt<2;++nt) {
    float inv = 1.0f / l_run[nt];
    const size_t rowg = (size_t)(bx*128 + w*32 + nt*16 + c);
#pragma unroll
    for (int mtd=0;mtd<8;++mtd) {
      hx4 ov;
#pragma unroll
      for (int i=0;i<4;++i) ov[i] = (half_t)(oacc[mtd][nt][i]*inv);
      *(hx4*)(Pacc + rowg*128 + mtd*16 + 4*q) = ov;
    }
    if (q == 0) {
      Pm[rowg] = m_run[nt];
      Pl[rowg] = l_run[nt];
    }
  }
}

// ---------------- Kernel 4: merge 8 key-split partials ----------------
__global__ __launch_bounds__(256) void merge_kernel(
    const float* __restrict__ Z, const half_t* __restrict__ Pacc,
    const float* __restrict__ Pm, const float* __restrict__ Pl,
    float* __restrict__ out)
{
  const int th = blockIdx.x*256 + threadIdx.x;
  const int r = th >> 5, cg = th & 31;
  const int qb = r >> 7, rr = r & 127;
  float mk[8], lk[8];
  float M = -1e30f;
#pragma unroll
  for (int k=0;k<8;++k) {
    int p = qb*8 + k;
    mk[k] = Pm[p*128 + rr];
    lk[k] = Pl[p*128 + rr];
    M = fmaxf(M, mk[k]);
  }
  float L = 0.f, wk[8];
#pragma unroll
  for (int k=0;k<8;++k) { wk[k] = lk[k]*__builtin_amdgcn_exp2f((mk[k]-M)*LOG2E); L += wk[k]; }
  float o0=0.f,o1=0.f,o2=0.f,o3=0.f;
#pragma unroll
  for (int k=0;k<8;++k) {
    int p = qb*8 + k;
    hx4 v = *(const hx4*)(Pacc + ((size_t)p*128 + rr)*128 + cg*4);
    o0 += wk[k]*(float)v[0]; o1 += wk[k]*(float)v[1];
    o2 += wk[k]*(float)v[2]; o3 += wk[k]*(float)v[3];
  }
  float invL = 1.0f / L;
  fx4 zv = *(const fx4*)(Z + (size_t)r*128 + cg*4);
  fx4 res;
  res[0] = (1.f-TAU)*zv[0] + TAU*o0*invL;
  res[1] = (1.f-TAU)*zv[1] + TAU*o1*invL;
  res[2] = (1.f-TAU)*zv[2] + TAU*o2*invL;
  res[3] = (1.f-TAU)*zv[3] + TAU*o3*invL;
  *(fx4*)(out + (size_t)r*128 + cg*4) = res;
}

extern "C" void kernel_launch(void* const* d_in, const int* in_sizes, int n_in,
                              void* d_out, int out_size, void* d_ws, size_t ws_size,
                              hipStream_t stream) {
  const float* Z  = (const float*)d_in[0];
  const float* W1 = (const float*)d_in[1];
  const float* b1 = (const float*)d_in[2];
  const float* W2 = (const float*)d_in[3];
  const float* b2 = (const float*)d_in[4];
  float* out = (float*)d_out;

  char* ws = (char*)d_ws;
  half_t* Thi  = (half_t*)(ws);                                   // 2 MB
  half_t* Zth  = (half_t*)(ws + (size_t)2*1024*1024);             // 2 MB
  half_t* Pacc = (half_t*)(ws + (size_t)4*1024*1024);             // 16 MB
  float*  Pm   = (float*)(ws + (size_t)4*1024*1024 + (size_t)512*128*128*2);
  float*  Pl   = Pm + 512*128;

  hipLaunchKernelGGL(mlp_kernel,   dim3(512),  dim3(256), 0, stream, Z, W1, b1, W2, b2, Thi);
  hipLaunchKernelGGL(ztrans_kernel,dim3(512),  dim3(256), 0, stream, Z, Zth);
  hipLaunchKernelGGL(flash_kernel, dim3(512),  dim3(256), 0, stream, Thi, Zth, Pacc, Pm, Pl);
  hipLaunchKernelGGL(merge_kernel, dim3(1024), dim3(256), 0, stream, Z, Pacc, Pm, Pl, out);
}

// Round 4
// 138.758 us; speedup vs baseline: 1.4645x; 1.2980x over previous
//
#include <hip/hip_runtime.h>

typedef _Float16 half_t;
typedef _Float16 hx8 __attribute__((ext_vector_type(8)));
typedef _Float16 hx4 __attribute__((ext_vector_type(4)));
typedef float fx4 __attribute__((ext_vector_type(4)));

#define LOG2E 1.44269504088896f
#define TAU 0.1f

// ---------------- Kernel 0: Wt[out][in] = (fp16) W[in][out] ----------------
// 8 blocks: bx 0..3 -> W1 strips, 4..7 -> W2 strips of 32 input-rows.
__global__ __launch_bounds__(256) void wtrans_kernel(
    const float* __restrict__ W1, const float* __restrict__ W2,
    half_t* __restrict__ W1t, half_t* __restrict__ W2t)
{
  __shared__ float tile[32*132];
  const int bx = blockIdx.x;
  const float* W = (bx & 4) ? W2 : W1;
  half_t* Wt = (bx & 4) ? W2t : W1t;
  const int i0 = (bx & 3) * 32;
  const int tid = threadIdx.x;
  const int r = tid >> 3, cb = tid & 7;
#pragma unroll
  for (int it=0; it<4; ++it) {
    int c4 = cb*4 + it*32;
    *(fx4*)(&tile[r*132 + c4]) = *(const fx4*)(W + (size_t)(i0+r)*128 + c4);
  }
  __syncthreads();
  const int o = tid >> 1, ih = (tid & 1)*16;
  hx8 v0, v1;
#pragma unroll
  for (int u=0;u<8;++u) v0[u] = (half_t)tile[(ih+u)*132 + o];
#pragma unroll
  for (int u=0;u<8;++u) v1[u] = (half_t)tile[(ih+8+u)*132 + o];
  *(hx8*)(Wt + (size_t)o*128 + i0 + ih)     = v0;
  *(hx8*)(Wt + (size_t)o*128 + i0 + ih + 8) = v1;
}

// ---------------- Kernel 1: T = relu(Z@W1+b1)@W2+b2 via MFMA ----------------
// grid 128 x 64 rows, 4 waves x 16 rows. Both layers computed TRANSPOSED
// (A = W-transposed rows, B = data rows) so fragment layouts chain with only
// one contiguous per-wave LDS roundtrip. Verified frag maps from flash_kernel:
// A[m=c][k=8q+j], B[n=c][k=8q+j], D[m=4q+i][n=c].
__global__ __launch_bounds__(256) void mlp_kernel(
    const float* __restrict__ Z, const half_t* __restrict__ W1t,
    const float* __restrict__ b1, const half_t* __restrict__ W2t,
    const float* __restrict__ b2, half_t* __restrict__ T)
{
  __shared__ half_t Hs[4][16*136];      // per-wave H[row][h], stride 136
  const int tid = threadIdx.x;
  const int w = tid >> 6, lane = tid & 63;
  const int q = lane >> 4, c = lane & 15;
  const int wrow = blockIdx.x*64 + w*16;

  // Layer 1: H^T = W1t @ Z^T.  B-frags = Z rows (fp32 -> fp16), pinned.
  hx8 zb[4];
#pragma unroll
  for (int ks=0;ks<4;++ks) {
    fx4 a = *(const fx4*)(Z + (size_t)(wrow + c)*128 + ks*32 + q*8);
    fx4 b = *(const fx4*)(Z + (size_t)(wrow + c)*128 + ks*32 + q*8 + 4);
#pragma unroll
    for (int u=0;u<4;++u) { zb[ks][u] = (half_t)a[u]; zb[ks][4+u] = (half_t)b[u]; }
  }
  fx4 acc[8];
#pragma unroll
  for (int mt=0;mt<8;++mt) acc[mt] = (fx4){0.f,0.f,0.f,0.f};
#pragma unroll
  for (int mt=0;mt<8;++mt)
#pragma unroll
    for (int ks=0;ks<4;++ks) {
      hx8 aw = *(const hx8*)(W1t + (size_t)(mt*16 + c)*128 + ks*32 + q*8);
      acc[mt] = __builtin_amdgcn_mfma_f32_16x16x32_f16(aw, zb[ks], acc[mt], 0,0,0);
    }
  // D1[h=16mt+4q+i][row=c] -> relu(+b1) -> Hs[w][c][h] (contiguous hx4 writes)
#pragma unroll
  for (int mt=0;mt<8;++mt) {
    fx4 bias = *(const fx4*)(b1 + mt*16 + 4*q);
    hx4 hv;
#pragma unroll
    for (int i=0;i<4;++i) {
      float h = acc[mt][i] + bias[i];
      hv[i] = (half_t)(h > 0.f ? h : 0.f);
    }
    *(hx4*)(&Hs[w][c*136 + mt*16 + 4*q]) = hv;
  }

  // Layer 2: T^T = W2t @ H^T.  B-frags = H rows from LDS.
  hx8 hb[4];
#pragma unroll
  for (int ks=0;ks<4;++ks) hb[ks] = *(const hx8*)(&Hs[w][c*136 + ks*32 + q*8]);
#pragma unroll
  for (int mt=0;mt<8;++mt) acc[mt] = (fx4){0.f,0.f,0.f,0.f};
#pragma unroll
  for (int mt=0;mt<8;++mt)
#pragma unroll
    for (int ks=0;ks<4;++ks) {
      hx8 aw = *(const hx8*)(W2t + (size_t)(mt*16 + c)*128 + ks*32 + q*8);
      acc[mt] = __builtin_amdgcn_mfma_f32_16x16x32_f16(aw, hb[ks], acc[mt], 0,0,0);
    }
  // D2[out2=16mt+4q+i][row=c] -> T[wrow+c][out2] (contiguous hx4 stores)
#pragma unroll
  for (int mt=0;mt<8;++mt) {
    fx4 bias = *(const fx4*)(b2 + mt*16 + 4*q);
    hx4 tv;
#pragma unroll
    for (int i=0;i<4;++i) tv[i] = (half_t)(acc[mt][i] + bias[i]);
    *(hx4*)(T + (size_t)(wrow + c)*128 + mt*16 + 4*q) = tv;
  }
}

// ---------------- Kernel 2: Zt[d][n] = (fp16) Z[n][d] ----------------
__global__ __launch_bounds__(256) void ztrans_kernel(
    const float* __restrict__ Z, half_t* __restrict__ Zth)
{
  __shared__ float tile[64*36];
  const int tid = threadIdx.x;
  const int nb = blockIdx.x >> 2;
  const int db = blockIdx.x & 3;
#pragma unroll
  for (int i=0;i<2;++i) {
    int fid = i*256 + tid;
    int r = fid >> 3, c4 = (fid & 7) * 4;
    *(fx4*)(&tile[r*36 + c4]) = *(const fx4*)(Z + (size_t)(nb*64 + r)*128 + db*32 + c4);
  }
  __syncthreads();
  const int cr = tid >> 3, j = tid & 7, n0 = j*8;
  hx8 hv;
#pragma unroll
  for (int idx=0;idx<8;++idx) hv[idx] = (half_t)tile[(n0+idx)*36 + cr];
  *(hx8*)(Zth + (size_t)(db*32 + cr)*8192 + nb*64 + n0) = hv;
}

// ---------------- Kernel 3: flash attention partials (reg-prefetch) ---------
__global__ __launch_bounds__(256,2) void flash_kernel(
    const half_t* __restrict__ T, const half_t* __restrict__ Zt,
    half_t* __restrict__ Pacc, float* __restrict__ Pm, float* __restrict__ Pl)
{
  __shared__ half_t Tks[16*512];
  __shared__ half_t Zts[16*512];
  __shared__ half_t Ps[4][32*72];
  const int tid = threadIdx.x;
  const int w = tid >> 6, lane = tid & 63;
  const int q = lane >> 4, c = lane & 15;
  const int bx = blockIdx.x;
  const int qb = bx >> 3, kh = bx & 7;
  const int wrow = qb*128 + w*32;

  hx8 bq[2][4];
#pragma unroll
  for (int nt=0;nt<2;++nt)
#pragma unroll
    for (int ks=0;ks<4;++ks)
      bq[nt][ks] = *(const hx8*)(T + (size_t)(wrow + nt*16 + c)*128 + ks*32 + q*8);

  fx4 oacc[8][2];
#pragma unroll
  for (int mtd=0;mtd<8;++mtd)
#pragma unroll
    for (int nt=0;nt<2;++nt) oacc[mtd][nt] = (fx4){0.f,0.f,0.f,0.f};
  float m_run[2] = {-1e30f,-1e30f};
  float l_run[2] = {0.f,0.f};

  hx8 pre[8];
  const int kbase = kh*1024;

  auto load_tile = [&](int kt0) {
    if (w < 2) {
#pragma unroll
      for (int i=0;i<8;++i) {
        int f = w*8 + i, mt = f >> 2, ks = f & 3;
        pre[i] = *(const hx8*)(T + (size_t)(kt0 + mt*16 + c)*128 + ks*32 + q*8);
      }
    } else {
#pragma unroll
      for (int i=0;i<8;++i) {
        int f2 = (w-2)*8 + i, mtd = f2 >> 1, ks2 = f2 & 1;
        pre[i] = *(const hx8*)(Zt + (size_t)(mtd*16 + c)*8192 + kt0 + ks2*32 + q*8);
      }
    }
  };
  auto store_tile = [&]() {
    if (w < 2) {
#pragma unroll
      for (int i=0;i<8;++i) { int f = w*8 + i; *(hx8*)(&Tks[f*512 + lane*8]) = pre[i]; }
    } else {
#pragma unroll
      for (int i=0;i<8;++i) { int f2 = (w-2)*8 + i; *(hx8*)(&Zts[f2*512 + lane*8]) = pre[i]; }
    }
  };

  load_tile(kbase);
  for (int t=0;t<16;++t) {
    __syncthreads();
    store_tile();
    __syncthreads();
    if (t < 15) load_tile(kbase + (t+1)*64);

    fx4 sacc[4][2];
#pragma unroll
    for (int mt=0;mt<4;++mt)
#pragma unroll
      for (int nt=0;nt<2;++nt) sacc[mt][nt] = (fx4){0.f,0.f,0.f,0.f};
#pragma unroll
    for (int ks=0;ks<4;++ks)
#pragma unroll
      for (int mt=0;mt<4;++mt) {
        hx8 ak = *(const hx8*)(&Tks[(mt*4+ks)*512 + lane*8]);
        sacc[mt][0] = __builtin_amdgcn_mfma_f32_16x16x32_f16(ak, bq[0][ks], sacc[mt][0], 0,0,0);
        sacc[mt][1] = __builtin_amdgcn_mfma_f32_16x16x32_f16(ak, bq[1][ks], sacc[mt][1], 0,0,0);
      }

#pragma unroll
    for (int nt=0;nt<2;++nt) {
      float mx = -1e30f;
#pragma unroll
      for (int mt=0;mt<4;++mt)
#pragma unroll
        for (int i=0;i<4;++i) mx = fmaxf(mx, sacc[mt][nt][i]);
      mx = fmaxf(mx, __shfl_xor(mx, 16, 64));
      mx = fmaxf(mx, __shfl_xor(mx, 32, 64));
      float mnew = fmaxf(m_run[nt], mx);
      float alpha = __builtin_amdgcn_exp2f((m_run[nt]-mnew)*LOG2E);
      m_run[nt] = mnew;
      float nb = mnew*LOG2E;
      float rs = 0.f;
#pragma unroll
      for (int mt=0;mt<4;++mt) {
        hx4 pk;
#pragma unroll
        for (int i=0;i<4;++i) {
          float p = __builtin_amdgcn_exp2f(sacc[mt][nt][i]*LOG2E - nb);
          rs += p;
          pk[i] = (half_t)p;
        }
        *(hx4*)(&Ps[w][(nt*16 + c)*72 + mt*16 + 4*q]) = pk;
      }
      rs += __shfl_xor(rs, 16, 64);
      rs += __shfl_xor(rs, 32, 64);
      l_run[nt] = l_run[nt]*alpha + rs;
#pragma unroll
      for (int mtd=0;mtd<8;++mtd)
#pragma unroll
        for (int i=0;i<4;++i) oacc[mtd][nt][i] *= alpha;
    }

#pragma unroll
    for (int ks2=0;ks2<2;++ks2) {
      hx8 bp0 = *(const hx8*)(&Ps[w][(c     )*72 + ks2*32 + q*8]);
      hx8 bp1 = *(const hx8*)(&Ps[w][(16 + c)*72 + ks2*32 + q*8]);
#pragma unroll
      for (int mtd=0;mtd<8;++mtd) {
        hx8 az = *(const hx8*)(&Zts[(mtd*2+ks2)*512 + lane*8]);
        oacc[mtd][0] = __builtin_amdgcn_mfma_f32_16x16x32_f16(az, bp0, oacc[mtd][0], 0,0,0);
        oacc[mtd][1] = __builtin_amdgcn_mfma_f32_16x16x32_f16(az, bp1, oacc[mtd][1], 0,0,0);
      }
    }
  }

#pragma unroll
  for (int nt=0;nt<2;++nt) {
    float inv = 1.0f / l_run[nt];
    const size_t rowg = (size_t)(bx*128 + w*32 + nt*16 + c);
#pragma unroll
    for (int mtd=0;mtd<8;++mtd) {
      hx4 ov;
#pragma unroll
      for (int i=0;i<4;++i) ov[i] = (half_t)(oacc[mtd][nt][i]*inv);
      *(hx4*)(Pacc + rowg*128 + mtd*16 + 4*q) = ov;
    }
    if (q == 0) {
      Pm[rowg] = m_run[nt];
      Pl[rowg] = l_run[nt];
    }
  }
}

// ---------------- Kernel 4: merge 8 key-split partials ----------------
__global__ __launch_bounds__(256) void merge_kernel(
    const float* __restrict__ Z, const half_t* __restrict__ Pacc,
    const float* __restrict__ Pm, const float* __restrict__ Pl,
    float* __restrict__ out)
{
  const int th = blockIdx.x*256 + threadIdx.x;
  const int r = th >> 5, cg = th & 31;
  const int qb = r >> 7, rr = r & 127;
  float mk[8], lk[8];
  float M = -1e30f;
#pragma unroll
  for (int k=0;k<8;++k) {
    int p = qb*8 + k;
    mk[k] = Pm[p*128 + rr];
    lk[k] = Pl[p*128 + rr];
    M = fmaxf(M, mk[k]);
  }
  float L = 0.f, wk[8];
#pragma unroll
  for (int k=0;k<8;++k) { wk[k] = lk[k]*__builtin_amdgcn_exp2f((mk[k]-M)*LOG2E); L += wk[k]; }
  float o0=0.f,o1=0.f,o2=0.f,o3=0.f;
#pragma unroll
  for (int k=0;k<8;++k) {
    int p = qb*8 + k;
    hx4 v = *(const hx4*)(Pacc + ((size_t)p*128 + rr)*128 + cg*4);
    o0 += wk[k]*(float)v[0]; o1 += wk[k]*(float)v[1];
    o2 += wk[k]*(float)v[2]; o3 += wk[k]*(float)v[3];
  }
  float invL = 1.0f / L;
  fx4 zv = *(const fx4*)(Z + (size_t)r*128 + cg*4);
  fx4 res;
  res[0] = (1.f-TAU)*zv[0] + TAU*o0*invL;
  res[1] = (1.f-TAU)*zv[1] + TAU*o1*invL;
  res[2] = (1.f-TAU)*zv[2] + TAU*o2*invL;
  res[3] = (1.f-TAU)*zv[3] + TAU*o3*invL;
  *(fx4*)(out + (size_t)r*128 + cg*4) = res;
}

extern "C" void kernel_launch(void* const* d_in, const int* in_sizes, int n_in,
                              void* d_out, int out_size, void* d_ws, size_t ws_size,
                              hipStream_t stream) {
  const float* Z  = (const float*)d_in[0];
  const float* W1 = (const float*)d_in[1];
  const float* b1 = (const float*)d_in[2];
  const float* W2 = (const float*)d_in[3];
  const float* b2 = (const float*)d_in[4];
  float* out = (float*)d_out;

  char* ws = (char*)d_ws;
  half_t* Thi  = (half_t*)(ws);                                   // 2 MB
  half_t* Zth  = (half_t*)(ws + (size_t)2*1024*1024);             // 2 MB
  half_t* Pacc = (half_t*)(ws + (size_t)4*1024*1024);             // 16 MB
  float*  Pm   = (float*)(ws + (size_t)4*1024*1024 + (size_t)512*128*128*2);
  float*  Pl   = Pm + 512*128;
  half_t* W1t  = (half_t*)(ws + (size_t)4*1024*1024 + (size_t)512*128*128*2 + (size_t)2*512*128*4);
  half_t* W2t  = W1t + 128*128;

  hipLaunchKernelGGL(wtrans_kernel, dim3(8),    dim3(256), 0, stream, W1, W2, W1t, W2t);
  hipLaunchKernelGGL(ztrans_kernel, dim3(512),  dim3(256), 0, stream, Z, Zth);
  hipLaunchKernelGGL(mlp_kernel,    dim3(128),  dim3(256), 0, stream, Z, W1t, b1, W2t, b2, Thi);
  hipLaunchKernelGGL(flash_kernel,  dim3(512),  dim3(256), 0, stream, Thi, Zth, Pacc, Pm, Pl);
  hipLaunchKernelGGL(merge_kernel,  dim3(1024), dim3(256), 0, stream, Z, Pacc, Pm, Pl, out);
}